// Round 7
// baseline (205.364 us; speedup 1.0000x reference)
//
#include <hip/hip_runtime.h>

#define NV 2708
#define INC 1433
#define XCOLS 1472        // padded X/W cols (23*64)
#define UDIM 2752         // padded U dims (43*64)
#define PSTR 2728         // pbuf stride in shorts
#define BSTR 2752
#define SLAB ((size_t)(2752*64))   // fp32 partial slab
#define MWPR 88
#define NSP 4             // proj split-K chunks (K-chunk 384; last 320)
#define NSU 11            // gemmU split-K chunks (2752 = 10*256 + 192)

typedef __attribute__((ext_vector_type(8))) short bf16x8;
typedef __attribute__((ext_vector_type(4))) float f32x4;
typedef __attribute__((ext_vector_type(4))) unsigned short u16x4;

__device__ __forceinline__ unsigned short f2bf(float f){
  union { float f; unsigned int i; } v; v.f = f;
  return (unsigned short)((v.i + 0x7fffu + ((v.i >> 16) & 1u)) >> 16);  // RNE
}

// convert one fp32 row (INC elems, 4B-aligned base) to bf16 with zero pad to
// XCOLS. float2 via parity shift: src+sh is 8B-aligned (sh in {0,1}).
__device__ __forceinline__ void conv_row(const float* __restrict__ src,
                                         unsigned short* __restrict__ dst, int tid){
  const int sh = ((unsigned int)((size_t)src >> 2)) & 1;
  if (tid == 0){ int ce = sh ? 0 : (INC - 1); dst[ce] = f2bf(src[ce]); }
  const float2* s2 = (const float2*)(src + sh);
  for (int c2 = tid; c2 < (INC - 1)/2; c2 += 256){   // 716 pairs
    float2 v = s2[c2];
    int c = sh + c2*2;
    dst[c]     = f2bf(v.x);
    dst[c + 1] = f2bf(v.y);
  }
  for (int c = INC + tid; c < XCOLS; c += 256) dst[c] = 0;
}

// ====== convert_all: X/W/A one-row blocks + U 64x64 tiles (Ubf AND UTbf) ====
__global__ __launch_bounds__(256) void convert_all(
    const float* __restrict__ X, const float* __restrict__ WK,
    const float* __restrict__ WQ, const float* __restrict__ WV,
    const float* __restrict__ U, const int* __restrict__ A,
    unsigned short* __restrict__ Xbf, unsigned short* __restrict__ Wbf,
    unsigned short* __restrict__ Ubf, unsigned short* __restrict__ UTbf,
    unsigned int* __restrict__ Abits)
{
  __shared__ __align__(16) float tpose[64][68];   // 17.4 KB (U-tile branch)
  const int bx = blockIdx.x;
  const int tid = threadIdx.x;
  if (bx < 2752){                      // X row (float2 parity trick)
    const int row = bx;
    unsigned short* dst = Xbf + (size_t)row*XCOLS;
    if (row < NV){
      conv_row(X + (size_t)row*INC, dst, tid);
    } else {
      u16x4 zz = {0,0,0,0};
      for (int c4 = tid; c4 < XCOLS/4; c4 += 256) *(u16x4*)(dst + c4*4) = zz;
    }
  } else if (bx < 2944){               // W row (192 rows)
    const int row = bx - 2752;
    const float* s = (row < 64) ? WK : (row < 128) ? WQ : WV;
    conv_row(s + (size_t)(row & 63)*INC, Wbf + (size_t)row*XCOLS, tid);
  } else if (bx < 5652){               // A row -> bitmask (int4, grouped layout)
    const int i = bx - 2944;
    const int lane = tid & 63, wave = tid >> 6;
    const int* arow = A + (size_t)i*NV;
    unsigned int* drow = Abits + (size_t)i*MWPR;
    for (int g = wave; g < 11; g += 4){
      int base = g*256 + lane*4;
      int4 v = make_int4(0,0,0,0);
      if (base < NV) v = *(const int4*)(arow + base);
      unsigned long long m0 = __ballot(v.x != 0);
      unsigned long long m1 = __ballot(v.y != 0);
      unsigned long long m2 = __ballot(v.z != 0);
      unsigned long long m3 = __ballot(v.w != 0);
      if (lane < 8){
        unsigned long long mm = (lane < 2) ? m0 : (lane < 4) ? m1 : (lane < 6) ? m2 : m3;
        drow[g*8 + lane] = (lane & 1) ? (unsigned int)(mm >> 32) : (unsigned int)mm;
      }
    }
  } else {                             // U 64x64 tile -> Ubf rows + UTbf rows
    const int t = bx - 5652;           // < 1849
    const int tx = t % 43, ty = t / 43;
    const int r0 = ty*64, c0 = tx*64;
    #pragma unroll
    for (int j = 0; j < 4; j++){
      int row = j*16 + (tid >> 4);     // U row within tile
      int c4  = (tid & 15)*4;          // U col within tile
      float4 v = make_float4(0.f,0.f,0.f,0.f);
      if (r0 + row < NV && c0 + c4 < NV)        // NV%4==0: float4 fully valid
        v = *(const float4*)(U + (size_t)(r0+row)*NV + c0 + c4);
      *(float4*)&tpose[row][c4] = v;
      u16x4 h = { f2bf(v.x), f2bf(v.y), f2bf(v.z), f2bf(v.w) };
      *(u16x4*)(Ubf + (size_t)(r0+row)*UDIM + c0 + c4) = h;
    }
    __syncthreads();
    const int i = tid >> 2;            // UT row within tile (UT row c0+i)
    #pragma unroll
    for (int j = 0; j < 4; j++){
      int kk = ((tid & 3) + j*4)*4;    // UT col (k) start
      u16x4 h = { f2bf(tpose[kk+0][i]), f2bf(tpose[kk+1][i]),
                  f2bf(tpose[kk+2][i]), f2bf(tpose[kk+3][i]) };
      *(u16x4*)(UTbf + (size_t)(c0+i)*UDIM + r0 + kk) = h;
    }
  }
}

// ===== proj: partials of {K,Q,V} = Xbf @ Wbf^T. grid (86,4,3). =============
// LDS-free: A and B fragments loaded straight from global (k-contiguous).
// 32-row m-tiles; K-chunk 384 (12 K32 steps); zero barriers.
__global__ __launch_bounds__(256) void proj(
    const unsigned short* __restrict__ Xbf, const unsigned short* __restrict__ Wbf,
    float* __restrict__ part)
{
  const int tid = threadIdx.x;
  const int lane = tid & 63, wave = tid >> 6, quad = lane >> 4, lr = lane & 15;
  const int m0 = blockIdx.x * 32;
  const int s  = blockIdx.y, z = blockIdx.z;
  const int kbeg = s * 384, kend = min(kbeg + 384, XCOLS);  // last chunk 320
  const int wm = (wave & 1) * 16, wn = (wave >> 1) * 32;
  const unsigned short* xr = Xbf + (size_t)(m0 + wm + lr)*XCOLS + quad*8;
  const unsigned short* w0 = Wbf + (size_t)(z*64 + wn + lr)*XCOLS + quad*8;
  const unsigned short* w1 = Wbf + (size_t)(z*64 + wn + 16 + lr)*XCOLS + quad*8;
  f32x4 acc[2] = {};

  for (int k0 = kbeg; k0 < kend; k0 += 32){
    bf16x8 af = *(const bf16x8*)(xr + k0);
    bf16x8 b0 = *(const bf16x8*)(w0 + k0);
    bf16x8 b1 = *(const bf16x8*)(w1 + k0);
    acc[0] = __builtin_amdgcn_mfma_f32_16x16x32_bf16(af, b0, acc[0], 0, 0, 0);
    acc[1] = __builtin_amdgcn_mfma_f32_16x16x32_bf16(af, b1, acc[1], 0, 0, 0);
  }
  float* dst = part + (size_t)(z*NSP + s) * SLAB;
  #pragma unroll
  for (int t = 0; t < 2; t++)
    #pragma unroll
    for (int e = 0; e < 4; e++)
      dst[(size_t)(m0 + wm + quad*4 + e)*64 + wn + t*16 + lr] = acc[t][e];
}

// K16f frag-linear ; QT16 [c][m] ; VTf frag-linear. grid (688, 3).
__global__ __launch_bounds__(256) void reduce_proj(
    const float* __restrict__ part, unsigned short* __restrict__ K16f,
    unsigned short* __restrict__ QT16, unsigned short* __restrict__ VTf)
{
  int idx = blockIdx.x*256 + threadIdx.x;       // < 2752*64
  int z = blockIdx.y;
  int m = idx >> 6, c = idx & 63;
  const float* base = part + (size_t)z*NSP*SLAB + idx;
  float v = 0.f;
  #pragma unroll
  for (int s = 0; s < NSP; s++) v += base[s*SLAB];
  unsigned short h = (m < NV) ? f2bf(v) : (unsigned short)0;
  if (z == 0){
    if (m < 2720) K16f[((m>>4)*2 + (c>>5))*512 + (m&15)*32 + (c&31)] = h;
  } else if (z == 1){
    QT16[(size_t)c*BSTR + m] = h;
  } else {
    if (m < 2720) VTf[(m>>5)*2048 + c*32 + (m&31)] = h;
  }
}

// ===== gemmU: partials of Arow @ Bcm^T. grid (86, 11). LDS-free. ============
// Used twice: G = UTbf @ Q (Bcm = QT16 [c][k]) and F = Ubf @ G2 (Bcm = G2T).
// 32-row tiles; K-chunk 256 (8 K32 steps); zero barriers.
__global__ __launch_bounds__(256) void gemmU(
    const unsigned short* __restrict__ Arow, const unsigned short* __restrict__ Bcm,
    float* __restrict__ part)
{
  const int tid = threadIdx.x;
  const int lane = tid & 63, wave = tid >> 6, quad = lane >> 4, lr = lane & 15;
  const int m0 = blockIdx.x * 32;
  const int s  = blockIdx.y;
  const int kbeg = s * 256, kend = min(kbeg + 256, UDIM);   // last chunk 192
  const int wm = (wave & 1) * 16, wn = (wave >> 1) * 32;
  const unsigned short* ar = Arow + (size_t)(m0 + wm + lr)*UDIM + quad*8;
  const unsigned short* b0r = Bcm + (size_t)(wn + lr)*BSTR + quad*8;
  const unsigned short* b1r = Bcm + (size_t)(wn + 16 + lr)*BSTR + quad*8;
  f32x4 acc[2] = {};

  for (int k0 = kbeg; k0 < kend; k0 += 32){
    bf16x8 af = *(const bf16x8*)(ar + k0);
    bf16x8 b0 = *(const bf16x8*)(b0r + k0);
    bf16x8 b1 = *(const bf16x8*)(b1r + k0);
    acc[0] = __builtin_amdgcn_mfma_f32_16x16x32_bf16(af, b0, acc[0], 0, 0, 0);
    acc[1] = __builtin_amdgcn_mfma_f32_16x16x32_bf16(af, b1, acc[1], 0, 0, 0);
  }
  float* dst = part + (size_t)s * SLAB;
  #pragma unroll
  for (int t = 0; t < 2; t++)
    #pragma unroll
    for (int e = 0; e < 4; e++)
      dst[(size_t)(m0 + wm + quad*4 + e)*64 + wn + t*16 + lr] = acc[t][e];
}

// G2T16[c][m] = bf16(G[m][c] * lmbd[m]/64), zero pads. grid 688.
__global__ __launch_bounds__(256) void reduce_g(
    const float* __restrict__ part, const float* __restrict__ lm,
    unsigned short* __restrict__ G2T)
{
  int idx = blockIdx.x*256 + threadIdx.x;
  int m = idx >> 6, c = idx & 63;
  const float* base = part + idx;
  float v = 0.f;
  #pragma unroll
  for (int s = 0; s < NSU; s++) v += base[s*SLAB];
  unsigned short h = 0;
  if (m < NV) h = f2bf(v * lm[m] * (1.0f/64.0f));
  G2T[(size_t)c*BSTR + m] = h;
}

// ====== fused: reduce-F + |F K^T| -> masked exp + row-sum -> P V ============
// 16 rows/block, 512 threads (8 waves), 170 blocks (1 block/CU, no tail).
__global__ __launch_bounds__(512) void fused_attn(
    const float* __restrict__ partF, const unsigned short* __restrict__ K16f,
    const unsigned int* __restrict__ Abits, const unsigned short* __restrict__ VTf,
    float* __restrict__ Hout)
{
  __shared__ __align__(16) unsigned short pbuf[16*PSTR];   // 87.3 KB
  __shared__ __align__(16) unsigned short fbuf[16*64];     // 2 KB
  __shared__ unsigned int mrow[16*MWPR];                   // 5.6 KB
  __shared__ float swave[8][16];
  __shared__ float rinv[16];
  __shared__ __align__(16) float obuf[4][256];             // 4 KB
  const int tid  = threadIdx.x;
  const int lane = tid & 63, wave = tid >> 6;
  const int quad = lane >> 4, lr = lane & 15;
  const int i0 = blockIdx.x * 16;

  // stage F rows (sum 11 slabs; rows >= NV are zero in part)
  #pragma unroll
  for (int h = 0; h < 2; h++){
    int idx = h*512 + tid;              // < 1024
    const float* base = partF + (size_t)(i0 + (idx >> 6))*64 + (idx & 63);
    float v = 0.f;
    #pragma unroll
    for (int s = 0; s < NSU; s++) v += base[s*SLAB];
    fbuf[idx] = f2bf(v);
  }
  for (int idx = tid; idx < 16*MWPR; idx += 512){
    int r = idx / MWPR;
    unsigned int v = 0;
    if (i0 + r < NV) v = Abits[(size_t)(i0 + r)*MWPR + (idx - r*MWPR)];
    mrow[idx] = v;
  }
  __syncthreads();

  const bf16x8 af0 = *(const bf16x8*)&fbuf[lr*64 + quad*8];
  const bf16x8 af1 = *(const bf16x8*)&fbuf[lr*64 + 32 + quad*8];
  float psum[4] = {0.f, 0.f, 0.f, 0.f};
  {
    int t = wave;
    const unsigned short* kb = K16f + t*1024 + lr*32 + quad*8;
    bf16x8 b0 = *(const bf16x8*)(kb);
    bf16x8 b1 = *(const bf16x8*)(kb + 512);
    while (t < 170){
      int tn = t + 8;
      bf16x8 n0 = b0, n1 = b1;
      if (tn < 170){
        const unsigned short* nb = K16f + tn*1024 + lr*32 + quad*8;
        n0 = *(const bf16x8*)(nb);
        n1 = *(const bf16x8*)(nb + 512);
      }
      f32x4 sv0 = {}, sv1 = {};
      sv0 = __builtin_amdgcn_mfma_f32_16x16x32_bf16(af0, b0, sv0, 0, 0, 0);
      sv1 = __builtin_amdgcn_mfma_f32_16x16x32_bf16(af1, b1, sv1, 0, 0, 0);
      f32x4 sv = sv0 + sv1;
      {
        int col = t*16 + lr;
        int ss = col & 255, ll = ss >> 2;
        int wsh = (col >> 8)*8 + (ss & 3)*2 + (ll >> 5);
        int bit = ll & 31;
        #pragma unroll
        for (int e = 0; e < 4; e++){
          int r = quad*4 + e;
          float p = 0.f;
          if ((mrow[r*MWPR + wsh] >> bit) & 1u) p = __expf(fabsf(sv[e]));
          psum[e] += p;
          pbuf[r*PSTR + col] = f2bf(p);
        }
      }
      b0 = n0; b1 = n1; t = tn;
    }
  }
  #pragma unroll
  for (int e = 0; e < 4; e++){
    float v = psum[e];
    #pragma unroll
    for (int o = 1; o <= 8; o <<= 1) v += __shfl_xor(v, o, 64);
    if (lr == 0) swave[wave][quad*4 + e] = v;
  }
  __syncthreads();
  if (tid < 16){
    float s = 0.f;
    #pragma unroll
    for (int w = 0; w < 8; w++) s += swave[w][tid];
    rinv[tid] = (s > 0.f) ? (1.f/s) : 0.f;
  }
  __syncthreads();

  const int c0 = (wave & 3) * 16;
  const int ktbeg = (wave >> 2) ? 43 : 0;
  const int ktend = (wave >> 2) ? 85 : 43;
  f32x4 acc = {};
  {
    bf16x8 bv = *(const bf16x8*)&VTf[ktbeg*2048 + (c0 + lr)*32 + quad*8];
    for (int kt = ktbeg; kt < ktend; kt++){
      bf16x8 bn = bv;
      if (kt + 1 < ktend) bn = *(const bf16x8*)&VTf[(kt+1)*2048 + (c0 + lr)*32 + quad*8];
      bf16x8 af = *(const bf16x8*)&pbuf[lr*PSTR + kt*32 + quad*8];
      acc = __builtin_amdgcn_mfma_f32_16x16x32_bf16(af, bv, acc, 0, 0, 0);
      bv = bn;
    }
  }
  if (wave >= 4) *(f32x4*)&obuf[wave & 3][lane*4] = acc;
  __syncthreads();
  if (wave < 4){
    f32x4 o = *(const f32x4*)&obuf[wave][lane*4];
    acc += o;
    #pragma unroll
    for (int e = 0; e < 4; e++){
      int r = quad*4 + e;
      int i = i0 + r;
      if (i < NV) Hout[(size_t)i*64 + c0 + lr] = acc[e] * rinv[r];
    }
  }
}

extern "C" void kernel_launch(void* const* d_in, const int* in_sizes, int n_in,
                              void* d_out, int out_size, void* d_ws, size_t ws_size,
                              hipStream_t stream){
  (void)in_sizes; (void)n_in; (void)out_size; (void)ws_size;
  const float* X  = (const float*)d_in[0];
  const int*   A  = (const int*)d_in[1];
  const float* U  = (const float*)d_in[2];
  const float* WK = (const float*)d_in[3];
  const float* WQ = (const float*)d_in[4];
  const float* WV = (const float*)d_in[5];
  const float* lm = (const float*)d_in[6];

  char* ws = (char*)d_ws;
  size_t off = 0;
  auto alloc = [&](size_t bytes){ size_t o = off; off = (off + bytes + 255) & ~(size_t)255; return o; };
  float*          part = (float*)(ws + alloc(24*SLAB*4));                      // 16.9 MB
  unsigned short* Ubf  = (unsigned short*)(ws + alloc((size_t)UDIM*UDIM*2));   // 15.15 MB
  unsigned short* UTbf = (unsigned short*)(ws + alloc((size_t)UDIM*UDIM*2));   // 15.15 MB
  unsigned short* Xbf  = (unsigned short*)(ws + alloc((size_t)UDIM*XCOLS*2));  // 8.10 MB
  unsigned short* Wbf  = (unsigned short*)(ws + alloc((size_t)192*XCOLS*2));
  unsigned short* K16f = (unsigned short*)(ws + alloc((size_t)170*1024*2));
  unsigned short* QT16 = (unsigned short*)(ws + alloc((size_t)64*BSTR*2));
  unsigned short* G2T  = (unsigned short*)(ws + alloc((size_t)64*BSTR*2));
  unsigned short* VTf  = (unsigned short*)(ws + alloc((size_t)85*2048*2));
  unsigned int*   Abits= (unsigned int*)(ws + alloc((size_t)NV*MWPR*4));
  // total ~59 MB

  convert_all<<<dim3(7501), 256, 0, stream>>>(X, WK, WQ, WV, U, A,
                                              Xbf, Wbf, Ubf, UTbf, Abits);
  proj<<<dim3(86, NSP, 3), 256, 0, stream>>>(Xbf, Wbf, part);
  reduce_proj<<<dim3(688, 3), 256, 0, stream>>>(part, K16f, QT16, VTf);
  gemmU<<<dim3(86, NSU), 256, 0, stream>>>(UTbf, QT16, part);     // G partials
  reduce_g<<<dim3(688), 256, 0, stream>>>(part, lm, G2T);
  gemmU<<<dim3(86, NSU), 256, 0, stream>>>(Ubf, G2T, part);       // F partials
  fused_attn<<<dim3(170), 512, 0, stream>>>(part, K16f, Abits, VTf, (float*)d_out);
}

// Round 8
// 176.504 us; speedup vs baseline: 1.1635x; 1.1635x over previous
//
#include <hip/hip_runtime.h>

#define NV 2708
#define INC 1433
#define XCOLS 1472        // padded X/W cols (23*64)
#define UDIM 2752         // padded U dims (43*64)
#define PSTR 2728         // pbuf stride in shorts
#define BSTR 2752
#define SLAB ((size_t)(2752*64))   // fp32 partial slab
#define MWPR 88
#define NSP 4             // proj split-K chunks (K-chunk 384; last 320)
#define NSU 11            // gemmU split-K chunks (2752 = 10*256 + 192)

typedef __attribute__((ext_vector_type(8))) short bf16x8;
typedef __attribute__((ext_vector_type(4))) float f32x4;
typedef __attribute__((ext_vector_type(4))) unsigned short u16x4;

__device__ __forceinline__ unsigned short f2bf(float f){
  union { float f; unsigned int i; } v; v.f = f;
  return (unsigned short)((v.i + 0x7fffu + ((v.i >> 16) & 1u)) >> 16);  // RNE
}

// convert one fp32 row (INC elems, 4B-aligned base) to bf16 with zero pad to
// XCOLS. float2 via parity shift: src+sh is 8B-aligned (sh in {0,1}).
__device__ __forceinline__ void conv_row(const float* __restrict__ src,
                                         unsigned short* __restrict__ dst, int tid){
  const int sh = ((unsigned int)((size_t)src >> 2)) & 1;
  if (tid == 0){ int ce = sh ? 0 : (INC - 1); dst[ce] = f2bf(src[ce]); }
  const float2* s2 = (const float2*)(src + sh);
  for (int c2 = tid; c2 < (INC - 1)/2; c2 += 256){   // 716 pairs
    float2 v = s2[c2];
    int c = sh + c2*2;
    dst[c]     = f2bf(v.x);
    dst[c + 1] = f2bf(v.y);
  }
  for (int c = INC + tid; c < XCOLS; c += 256) dst[c] = 0;
}

// ====== convert_all: X/W/A one-row blocks + U 64x64 tiles (Ubf AND UTbf) ====
__global__ __launch_bounds__(256) void convert_all(
    const float* __restrict__ X, const float* __restrict__ WK,
    const float* __restrict__ WQ, const float* __restrict__ WV,
    const float* __restrict__ U, const int* __restrict__ A,
    unsigned short* __restrict__ Xbf, unsigned short* __restrict__ Wbf,
    unsigned short* __restrict__ Ubf, unsigned short* __restrict__ UTbf,
    unsigned int* __restrict__ Abits)
{
  __shared__ __align__(16) float tpose[64][68];   // 17.4 KB (U-tile branch)
  const int bx = blockIdx.x;
  const int tid = threadIdx.x;
  if (bx < 2752){                      // X row (float2 parity trick)
    const int row = bx;
    unsigned short* dst = Xbf + (size_t)row*XCOLS;
    if (row < NV){
      conv_row(X + (size_t)row*INC, dst, tid);
    } else {
      u16x4 zz = {0,0,0,0};
      for (int c4 = tid; c4 < XCOLS/4; c4 += 256) *(u16x4*)(dst + c4*4) = zz;
    }
  } else if (bx < 2944){               // W row (192 rows)
    const int row = bx - 2752;
    const float* s = (row < 64) ? WK : (row < 128) ? WQ : WV;
    conv_row(s + (size_t)(row & 63)*INC, Wbf + (size_t)row*XCOLS, tid);
  } else if (bx < 5652){               // A row -> bitmask (int4, grouped layout)
    const int i = bx - 2944;
    const int lane = tid & 63, wave = tid >> 6;
    const int* arow = A + (size_t)i*NV;
    unsigned int* drow = Abits + (size_t)i*MWPR;
    for (int g = wave; g < 11; g += 4){
      int base = g*256 + lane*4;
      int4 v = make_int4(0,0,0,0);
      if (base < NV) v = *(const int4*)(arow + base);
      unsigned long long m0 = __ballot(v.x != 0);
      unsigned long long m1 = __ballot(v.y != 0);
      unsigned long long m2 = __ballot(v.z != 0);
      unsigned long long m3 = __ballot(v.w != 0);
      if (lane < 8){
        unsigned long long mm = (lane < 2) ? m0 : (lane < 4) ? m1 : (lane < 6) ? m2 : m3;
        drow[g*8 + lane] = (lane & 1) ? (unsigned int)(mm >> 32) : (unsigned int)mm;
      }
    }
  } else {                             // U 64x64 tile -> Ubf rows + UTbf rows
    const int t = bx - 5652;           // < 1849
    const int tx = t % 43, ty = t / 43;
    const int r0 = ty*64, c0 = tx*64;
    #pragma unroll
    for (int j = 0; j < 4; j++){
      int row = j*16 + (tid >> 4);     // U row within tile
      int c4  = (tid & 15)*4;          // U col within tile
      float4 v = make_float4(0.f,0.f,0.f,0.f);
      if (r0 + row < NV && c0 + c4 < NV)        // NV%4==0: float4 fully valid
        v = *(const float4*)(U + (size_t)(r0+row)*NV + c0 + c4);
      *(float4*)&tpose[row][c4] = v;
      u16x4 h = { f2bf(v.x), f2bf(v.y), f2bf(v.z), f2bf(v.w) };
      *(u16x4*)(Ubf + (size_t)(r0+row)*UDIM + c0 + c4) = h;
    }
    __syncthreads();
    const int i = tid >> 2;            // UT row within tile (UT row c0+i)
    #pragma unroll
    for (int j = 0; j < 4; j++){
      int kk = ((tid & 3) + j*4)*4;    // UT col (k) start
      u16x4 h = { f2bf(tpose[kk+0][i]), f2bf(tpose[kk+1][i]),
                  f2bf(tpose[kk+2][i]), f2bf(tpose[kk+3][i]) };
      *(u16x4*)(UTbf + (size_t)(c0+i)*UDIM + r0 + kk) = h;
    }
  }
}

// ===== proj: partials of {K,Q,V} = Xbf @ Wbf^T. grid (86,4,3). ==============
// 32-row m-tiles, LDS-staged A+B (gemmU recipe), K-chunk 384. 1032 blocks.
__global__ __launch_bounds__(256) void proj(
    const unsigned short* __restrict__ Xbf, const unsigned short* __restrict__ Wbf,
    float* __restrict__ part)
{
  __shared__ __align__(16) unsigned short At[32*72];
  __shared__ __align__(16) unsigned short Bt[64*72];
  const int tid = threadIdx.x;
  const int lane = tid & 63, wave = tid >> 6, quad = lane >> 4, lr = lane & 15;
  const int m0 = blockIdx.x * 32;
  const int s  = blockIdx.y, z = blockIdx.z;
  const int kbeg = s * 384, kend = min(kbeg + 384, XCOLS);  // last chunk 320
  const int wm = (wave & 1) * 16, wn = (wave >> 1) * 32;
  const unsigned short* Wz = Wbf + (size_t)z*64*XCOLS;
  const int arow = tid >> 3, aseg = tid & 7;
  const int brow = tid >> 2, bseg = tid & 3;
  f32x4 acc[2] = {};

  for (int k0 = kbeg; k0 < kend; k0 += 64){
    *(bf16x8*)&At[arow*72 + aseg*8] =
        *(const bf16x8*)(Xbf + (size_t)(m0+arow)*XCOLS + k0 + aseg*8);
    {
      const unsigned short* b = Wz + (size_t)brow*XCOLS + k0 + bseg*16;
      *(bf16x8*)&Bt[brow*72 + bseg*16]     = *(const bf16x8*)(b);
      *(bf16x8*)&Bt[brow*72 + bseg*16 + 8] = *(const bf16x8*)(b + 8);
    }
    __syncthreads();
    #pragma unroll
    for (int ks = 0; ks < 2; ks++){
      bf16x8 af = *(const bf16x8*)&At[(wm + lr)*72 + ks*32 + quad*8];
      bf16x8 bv[2];
      #pragma unroll
      for (int t = 0; t < 2; t++)
        bv[t] = *(const bf16x8*)&Bt[(wn + t*16 + lr)*72 + ks*32 + quad*8];
      #pragma unroll
      for (int t = 0; t < 2; t++)
        acc[t] = __builtin_amdgcn_mfma_f32_16x16x32_bf16(af, bv[t], acc[t], 0, 0, 0);
    }
    __syncthreads();
  }
  float* dst = part + (size_t)(z*NSP + s) * SLAB;
  #pragma unroll
  for (int t = 0; t < 2; t++)
    #pragma unroll
    for (int e = 0; e < 4; e++)
      dst[(size_t)(m0 + wm + quad*4 + e)*64 + wn + t*16 + lr] = acc[t][e];
}

// K16f frag-linear ; QT16 [c][m] ; VTf frag-linear. grid (688, 3).
__global__ __launch_bounds__(256) void reduce_proj(
    const float* __restrict__ part, unsigned short* __restrict__ K16f,
    unsigned short* __restrict__ QT16, unsigned short* __restrict__ VTf)
{
  int idx = blockIdx.x*256 + threadIdx.x;       // < 2752*64
  int z = blockIdx.y;
  int m = idx >> 6, c = idx & 63;
  const float* base = part + (size_t)z*NSP*SLAB + idx;
  float v = 0.f;
  #pragma unroll
  for (int s = 0; s < NSP; s++) v += base[s*SLAB];
  unsigned short h = (m < NV) ? f2bf(v) : (unsigned short)0;
  if (z == 0){
    if (m < 2720) K16f[((m>>4)*2 + (c>>5))*512 + (m&15)*32 + (c&31)] = h;
  } else if (z == 1){
    QT16[(size_t)c*BSTR + m] = h;
  } else {
    if (m < 2720) VTf[(m>>5)*2048 + c*32 + (m&31)] = h;
  }
}

// ===== gemmU: partials of Arow @ Bcm^T. grid (86, 11). 32-row tiles. ========
// Used twice: G = UTbf @ Q  (Bcm = QT16 [c][k])  and  F = Ubf @ G2 (Bcm = G2T).
// A-stage row-major bf16x8 (conflict-free); K-chunk 256 -> 4 K64 iters.
__global__ __launch_bounds__(256) void gemmU(
    const unsigned short* __restrict__ Arow, const unsigned short* __restrict__ Bcm,
    float* __restrict__ part)
{
  __shared__ __align__(16) unsigned short At[32*72];
  __shared__ __align__(16) unsigned short Bt[64*72];
  const int tid = threadIdx.x;
  const int lane = tid & 63, wave = tid >> 6, quad = lane >> 4, lr = lane & 15;
  const int m0 = blockIdx.x * 32;
  const int s  = blockIdx.y;
  const int kbeg = s * 256, kend = min(kbeg + 256, UDIM);   // last chunk 192
  const int wm = (wave & 1) * 16, wn = (wave >> 1) * 32;
  const int arow = tid >> 3, aseg = tid & 7;
  const int bc = tid >> 2, bseg = tid & 3;
  f32x4 acc[2] = {};

  for (int k0 = kbeg; k0 < kend; k0 += 64){
    *(bf16x8*)&At[arow*72 + aseg*8] =
        *(const bf16x8*)(Arow + (size_t)(m0+arow)*UDIM + k0 + aseg*8);
    {
      const unsigned short* b = Bcm + (size_t)bc*BSTR + k0 + bseg*16;
      *(bf16x8*)&Bt[bc*72 + bseg*16]     = *(const bf16x8*)(b);
      *(bf16x8*)&Bt[bc*72 + bseg*16 + 8] = *(const bf16x8*)(b + 8);
    }
    __syncthreads();
    #pragma unroll
    for (int ks = 0; ks < 2; ks++){
      bf16x8 af = *(const bf16x8*)&At[(wm + lr)*72 + ks*32 + quad*8];
      bf16x8 bv[2];
      #pragma unroll
      for (int t = 0; t < 2; t++)
        bv[t] = *(const bf16x8*)&Bt[(wn + t*16 + lr)*72 + ks*32 + quad*8];
      #pragma unroll
      for (int t = 0; t < 2; t++)
        acc[t] = __builtin_amdgcn_mfma_f32_16x16x32_bf16(af, bv[t], acc[t], 0, 0, 0);
    }
    __syncthreads();
  }
  float* dst = part + (size_t)s * SLAB;
  #pragma unroll
  for (int t = 0; t < 2; t++)
    #pragma unroll
    for (int e = 0; e < 4; e++)
      dst[(size_t)(m0 + wm + quad*4 + e)*64 + wn + t*16 + lr] = acc[t][e];
}

// G2T16[c][m] = bf16(G[m][c] * lmbd[m]/64), zero pads. grid 688.
__global__ __launch_bounds__(256) void reduce_g(
    const float* __restrict__ part, const float* __restrict__ lm,
    unsigned short* __restrict__ G2T)
{
  int idx = blockIdx.x*256 + threadIdx.x;
  int m = idx >> 6, c = idx & 63;
  const float* base = part + idx;
  float v = 0.f;
  #pragma unroll
  for (int s = 0; s < NSU; s++) v += base[s*SLAB];
  unsigned short h = 0;
  if (m < NV) h = f2bf(v * lm[m] * (1.0f/64.0f));
  G2T[(size_t)c*BSTR + m] = h;
}

// ====== fused: reduce-F + |F K^T| -> masked exp + row-sum -> P V ============
// 16 rows/block, 512 threads (8 waves), 170 blocks (1 block/CU, no tail).
__global__ __launch_bounds__(512) void fused_attn(
    const float* __restrict__ partF, const unsigned short* __restrict__ K16f,
    const unsigned int* __restrict__ Abits, const unsigned short* __restrict__ VTf,
    float* __restrict__ Hout)
{
  __shared__ __align__(16) unsigned short pbuf[16*PSTR];   // 87.3 KB
  __shared__ __align__(16) unsigned short fbuf[16*64];     // 2 KB
  __shared__ unsigned int mrow[16*MWPR];                   // 5.6 KB
  __shared__ float swave[8][16];
  __shared__ float rinv[16];
  __shared__ __align__(16) float obuf[4][256];             // 4 KB
  const int tid  = threadIdx.x;
  const int lane = tid & 63, wave = tid >> 6;
  const int quad = lane >> 4, lr = lane & 15;
  const int i0 = blockIdx.x * 16;

  // stage F rows (sum 11 slabs; rows >= NV are zero in part)
  #pragma unroll
  for (int h = 0; h < 2; h++){
    int idx = h*512 + tid;              // < 1024
    const float* base = partF + (size_t)(i0 + (idx >> 6))*64 + (idx & 63);
    float v = 0.f;
    #pragma unroll
    for (int s = 0; s < NSU; s++) v += base[s*SLAB];
    fbuf[idx] = f2bf(v);
  }
  for (int idx = tid; idx < 16*MWPR; idx += 512){
    int r = idx / MWPR;
    unsigned int v = 0;
    if (i0 + r < NV) v = Abits[(size_t)(i0 + r)*MWPR + (idx - r*MWPR)];
    mrow[idx] = v;
  }
  __syncthreads();

  const bf16x8 af0 = *(const bf16x8*)&fbuf[lr*64 + quad*8];
  const bf16x8 af1 = *(const bf16x8*)&fbuf[lr*64 + 32 + quad*8];
  float psum[4] = {0.f, 0.f, 0.f, 0.f};
  {
    int t = wave;
    const unsigned short* kb = K16f + t*1024 + lr*32 + quad*8;
    bf16x8 b0 = *(const bf16x8*)(kb);
    bf16x8 b1 = *(const bf16x8*)(kb + 512);
    while (t < 170){
      int tn = t + 8;
      bf16x8 n0 = b0, n1 = b1;
      if (tn < 170){
        const unsigned short* nb = K16f + tn*1024 + lr*32 + quad*8;
        n0 = *(const bf16x8*)(nb);
        n1 = *(const bf16x8*)(nb + 512);
      }
      f32x4 sv0 = {}, sv1 = {};
      sv0 = __builtin_amdgcn_mfma_f32_16x16x32_bf16(af0, b0, sv0, 0, 0, 0);
      sv1 = __builtin_amdgcn_mfma_f32_16x16x32_bf16(af1, b1, sv1, 0, 0, 0);
      f32x4 sv = sv0 + sv1;
      {
        int col = t*16 + lr;
        int ss = col & 255, ll = ss >> 2;
        int wsh = (col >> 8)*8 + (ss & 3)*2 + (ll >> 5);
        int bit = ll & 31;
        #pragma unroll
        for (int e = 0; e < 4; e++){
          int r = quad*4 + e;
          float p = 0.f;
          if ((mrow[r*MWPR + wsh] >> bit) & 1u) p = __expf(fabsf(sv[e]));
          psum[e] += p;
          pbuf[r*PSTR + col] = f2bf(p);
        }
      }
      b0 = n0; b1 = n1; t = tn;
    }
  }
  #pragma unroll
  for (int e = 0; e < 4; e++){
    float v = psum[e];
    #pragma unroll
    for (int o = 1; o <= 8; o <<= 1) v += __shfl_xor(v, o, 64);
    if (lr == 0) swave[wave][quad*4 + e] = v;
  }
  __syncthreads();
  if (tid < 16){
    float s = 0.f;
    #pragma unroll
    for (int w = 0; w < 8; w++) s += swave[w][tid];
    rinv[tid] = (s > 0.f) ? (1.f/s) : 0.f;
  }
  __syncthreads();

  const int c0 = (wave & 3) * 16;
  const int ktbeg = (wave >> 2) ? 43 : 0;
  const int ktend = (wave >> 2) ? 85 : 43;
  f32x4 acc = {};
  {
    bf16x8 bv = *(const bf16x8*)&VTf[ktbeg*2048 + (c0 + lr)*32 + quad*8];
    for (int kt = ktbeg; kt < ktend; kt++){
      bf16x8 bn = bv;
      if (kt + 1 < ktend) bn = *(const bf16x8*)&VTf[(kt+1)*2048 + (c0 + lr)*32 + quad*8];
      bf16x8 af = *(const bf16x8*)&pbuf[lr*PSTR + kt*32 + quad*8];
      acc = __builtin_amdgcn_mfma_f32_16x16x32_bf16(af, bv, acc, 0, 0, 0);
      bv = bn;
    }
  }
  if (wave >= 4) *(f32x4*)&obuf[wave & 3][lane*4] = acc;
  __syncthreads();
  if (wave < 4){
    f32x4 o = *(const f32x4*)&obuf[wave][lane*4];
    acc += o;
    #pragma unroll
    for (int e = 0; e < 4; e++){
      int r = quad*4 + e;
      int i = i0 + r;
      if (i < NV) Hout[(size_t)i*64 + c0 + lr] = acc[e] * rinv[r];
    }
  }
}

extern "C" void kernel_launch(void* const* d_in, const int* in_sizes, int n_in,
                              void* d_out, int out_size, void* d_ws, size_t ws_size,
                              hipStream_t stream){
  (void)in_sizes; (void)n_in; (void)out_size; (void)ws_size;
  const float* X  = (const float*)d_in[0];
  const int*   A  = (const int*)d_in[1];
  const float* U  = (const float*)d_in[2];
  const float* WK = (const float*)d_in[3];
  const float* WQ = (const float*)d_in[4];
  const float* WV = (const float*)d_in[5];
  const float* lm = (const float*)d_in[6];

  char* ws = (char*)d_ws;
  size_t off = 0;
  auto alloc = [&](size_t bytes){ size_t o = off; off = (off + bytes + 255) & ~(size_t)255; return o; };
  float*          part = (float*)(ws + alloc(12*SLAB*4));                      // 8.45 MB
  unsigned short* Ubf  = (unsigned short*)(ws + alloc((size_t)UDIM*UDIM*2));   // 15.15 MB
  unsigned short* UTbf = (unsigned short*)(ws + alloc((size_t)UDIM*UDIM*2));   // 15.15 MB
  unsigned short* Xbf  = (unsigned short*)(ws + alloc((size_t)UDIM*XCOLS*2));  // 8.10 MB
  unsigned short* Wbf  = (unsigned short*)(ws + alloc((size_t)192*XCOLS*2));
  unsigned short* K16f = (unsigned short*)(ws + alloc((size_t)170*1024*2));
  unsigned short* QT16 = (unsigned short*)(ws + alloc((size_t)64*BSTR*2));
  unsigned short* G2T  = (unsigned short*)(ws + alloc((size_t)64*BSTR*2));
  unsigned short* VTf  = (unsigned short*)(ws + alloc((size_t)85*2048*2));
  unsigned int*   Abits= (unsigned int*)(ws + alloc((size_t)NV*MWPR*4));
  // total ~51 MB

  convert_all<<<dim3(7501), 256, 0, stream>>>(X, WK, WQ, WV, U, A,
                                              Xbf, Wbf, Ubf, UTbf, Abits);
  proj<<<dim3(86, NSP, 3), 256, 0, stream>>>(Xbf, Wbf, part);
  reduce_proj<<<dim3(688, 3), 256, 0, stream>>>(part, K16f, QT16, VTf);
  gemmU<<<dim3(86, NSU), 256, 0, stream>>>(UTbf, QT16, part);     // G partials
  reduce_g<<<dim3(688), 256, 0, stream>>>(part, lm, G2T);
  gemmU<<<dim3(86, NSU), 256, 0, stream>>>(Ubf, G2T, part);       // F partials
  fused_attn<<<dim3(170), 512, 0, stream>>>(part, K16f, Abits, VTf, (float*)d_out);
}